// Round 7
// baseline (240.804 us; speedup 1.0000x reference)
//
#include <hip/hip_runtime.h>
#include <hip/hip_bf16.h>
#include <stdint.h>

#define TOK   256
#define NOBJ  64
#define NDEMO 16
#define BATCH 256
#define SEQ   1105              /* 1 + 16*65 + 64 */
#define NDG   (NDEMO * BATCH)   /* 4096 demo groups */
#define NGRP  (NDG + BATCH)     /* 4352 total groups */
#define NQT   (NGRP * 4)        /* 17408 quarter-tiles (16 rows each) */
#define NG    8                 /* quarter-tiles per obj block */
#define OBJ_BLKS   (NQT / NG)   /* 2176 */
#define ACT_BLKS   512
#define INSTR_BLKS 128
#define TOTAL_BLKS (ACT_BLKS + INSTR_BLKS + OBJ_BLKS)

typedef __bf16 bf16x8 __attribute__((ext_vector_type(8)));
typedef float  f32x4  __attribute__((ext_vector_type(4)));

static __device__ __forceinline__ unsigned pack_bf16x2(float a, float b) {
    unsigned ua = __float_as_uint(a);
    unsigned ub = __float_as_uint(b);
    unsigned ra = (ua + 0x7FFFu + ((ua >> 16) & 1u)) >> 16;
    unsigned rb = (ub + 0x7FFFu + ((ub >> 16) & 1u)) >> 16;
    return (ra & 0xFFFFu) | (rb << 16);
}

static __device__ __forceinline__ uint16_t f32_to_bf16_bits(float a) {
    unsigned ua = __float_as_uint(a);
    return (uint16_t)((ua + 0x7FFFu + ((ua >> 16) & 1u)) >> 16);
}

static __device__ __forceinline__ bf16x8 pack8(float4 lo, float4 hi) {
    union { uint4 u; bf16x8 b; } r;
    r.u.x = pack_bf16x2(lo.x, lo.y);
    r.u.y = pack_bf16x2(lo.z, lo.w);
    r.u.z = pack_bf16x2(hi.x, hi.y);
    r.u.w = pack_bf16x2(hi.z, hi.w);
    return r.b;
}

// direct global->LDS, 16B per lane (dest linear: wave-uniform base + lane*16)
static __device__ __forceinline__ void gload_lds16(const float* g, void* l) {
    __builtin_amdgcn_global_load_lds(
        (const __attribute__((address_space(1))) uint32_t*)g,
        (__attribute__((address_space(3))) uint32_t*)l,
        16, 0, 0);
}

// ---------------------------------------------------------------------------
// Prologue: W_obj (f32 [k=256][t=256]) -> Wf, bf16 in MFMA fragment order:
// chunk q = ((wc*4 + j)*8 + s)*64 + lane  holds Wt[t = wc*64+j*16+(lane&15)]
// [k = s*32+(lane>>4)*8 .. +7], so each wave's B-preload is contiguous 1KB.
// ---------------------------------------------------------------------------
__global__ void wconv_frag_kernel(const float* __restrict__ W, uint16_t* __restrict__ Wf) {
    int q = blockIdx.x * 256 + threadIdx.x;   // 8192 chunks of 16B
    int lane = q & 63;
    int s  = (q >> 6) & 7;
    int j  = (q >> 9) & 3;
    int wc = (q >> 11) & 3;
    int tcol = wc * 64 + j * 16 + (lane & 15);
    int k0   = s * 32 + (lane >> 4) * 8;
    uint4 w;
    unsigned p[4];
#pragma unroll
    for (int h = 0; h < 4; ++h) {
        float a = W[(size_t)(k0 + 2 * h)     * TOK + tcol];
        float b = W[(size_t)(k0 + 2 * h + 1) * TOK + tcol];
        p[h] = pack_bf16x2(a, b);
    }
    w.x = p[0]; w.y = p[1]; w.z = p[2]; w.w = p[3];
    *reinterpret_cast<uint4*>(Wf + (size_t)q * 8) = w;
}

// ---------------------------------------------------------------------------
// Fused kernel. Grid roles:
//   [0, 512)         : action rows (8 per block)
//   [512, 640)       : instr rows (2 per block)
//   [640, 640+2176)  : obj GEMM, NG=8 16-row quarter-tiles per block,
//                      TRIPLE-buffered global_load_lds, 2-ahead stage,
//                      store-aware counted vmcnt. 3 blocks/CU target.
// ---------------------------------------------------------------------------
__global__ __launch_bounds__(256, 3) void fused_kernel(
    const float* __restrict__ demo_obj,   // (16,256,64,256)
    const float* __restrict__ cur,        // (256,64,256)
    const float* __restrict__ b_obj,      // (256,)
    const __bf16* __restrict__ Wf,        // fragment-ordered bf16 weights
    const float* __restrict__ demo_act,   // (16,256,7)
    const float* __restrict__ W_act,      // (7,256)
    const float* __restrict__ b_act,      // (256,)
    const float* __restrict__ instr,      // (256,768)
    const float* __restrict__ W_instr,    // (768,256)
    const float* __restrict__ b_instr,    // (256,)
    float* __restrict__ out)              // (256,1105,256)
{
    __shared__ __align__(16) float lds[3 * 16 * TOK];   // 48 KB: 3 x 16-row f32 tiles
    int blk = blockIdx.x;
    int tid = threadIdx.x;

    if (blk >= ACT_BLKS + INSTR_BLKS) {
        // ================= obj GEMM =================
        int ob = blk - (ACT_BLKS + INSTR_BLKS);
        int h0 = ob * NG;   // first quarter-tile; blocks never straddle demo/cur
        const float* base = (h0 < 4 * NDG)
            ? demo_obj + (size_t)h0 * (16 * TOK)
            : cur + (size_t)(h0 - 4 * NDG) * (16 * TOK);

        int wave = tid >> 6, lane = tid & 63;
        int l15 = lane & 15, l4 = lane >> 4;
        int n0 = wave * 64;

        // staging geometry: slot = i*256+tid; r = i*4+wave; sc = lane
        auto STAGE = [&](int it, int bsel) {
            const float* sb = base + (size_t)it * (16 * TOK);
            float* dst = lds + bsel * (16 * TOK);
#pragma unroll
            for (int i = 0; i < 4; ++i) {
                int r = i * 4 + wave;
                int gch = r * 64 + (lane ^ (r & 7));   // pre-swizzled global source
                gload_lds16(sb + (size_t)gch * 4, dst + (size_t)(i * 256 + tid) * 4);
            }
        };

        // ---- B preload FIRST (32 contiguous 1KB wave-loads, 128 VGPR) ----
        bf16x8 bf[4][8];
        {
            const __bf16* fb = Wf + ((size_t)wave * 32 * 64 + lane) * 8;
#pragma unroll
            for (int j = 0; j < 4; ++j)
#pragma unroll
                for (int s = 0; s < 8; ++s)
                    bf[j][s] = *reinterpret_cast<const bf16x8*>(fb + (size_t)(j * 8 + s) * 64 * 8);
        }
        // launder: compiler's wait for B lands here (prologue), not in-loop;
        // our explicit vmcnt(4) at it=0 also covers B (older in the FIFO).
#pragma unroll
        for (int j = 0; j < 4; ++j)
#pragma unroll
            for (int s = 0; s < 8; ++s)
                asm volatile("" : "+v"(bf[j][s]));

        float bv[4];
#pragma unroll
        for (int j = 0; j < 4; ++j) bv[j] = b_obj[n0 + j * 16 + l15];

        // ---- stage first two tiles ----
        STAGE(0, 0);
        STAGE(1, 1);

        int bc = 0;   // buffer of tile `it`
#pragma unroll 1
        for (int it = 0; it < NG; ++it) {
            // Wait for L_it without draining newer ops.
            // newer-than-L_it: it==0: L1(4); 1<=it<NG-1: L_{it+1}(4)+S_{it-1}(16);
            // it==NG-1: S_{it-1}(16).
            if (it == 0)           asm volatile("s_waitcnt vmcnt(4)"  ::: "memory");
            else if (it == NG - 1) asm volatile("s_waitcnt vmcnt(16)" ::: "memory");
            else                   asm volatile("s_waitcnt vmcnt(20)" ::: "memory");
            __builtin_amdgcn_s_barrier();           // raw: no implicit drain
            __builtin_amdgcn_sched_barrier(0);

            // stage 2-ahead into buffer (it+2)%3 == buffer of it-1 (reads done)
            if (it + 2 < NG) {
                int bs = bc >= 1 ? bc - 1 : bc + 2;   // (it+2)%3
                STAGE(it + 2, bs);
            }

            const float* buf = lds + bc * (16 * TOK);

            f32x4 acc[4];
#pragma unroll
            for (int j = 0; j < 4; ++j) {
                f32x4 z = {0.0f, 0.0f, 0.0f, 0.0f};
                acc[j] = z;
            }

#pragma unroll
            for (int s = 0; s < 8; ++s) {
                int c0 = s * 8 + l4 * 2;
                float4 lo = *reinterpret_cast<const float4*>(buf + l15 * TOK + ((c0 ^ (l15 & 7)) * 4));
                float4 hi = *reinterpret_cast<const float4*>(buf + l15 * TOK + (((c0 + 1) ^ (l15 & 7)) * 4));
                bf16x8 a = pack8(lo, hi);
#pragma unroll
                for (int j = 0; j < 4; ++j)
                    acc[j] = __builtin_amdgcn_mfma_f32_16x16x32_bf16(a, bf[j][s], acc[j], 0, 0, 0);
            }

            // ---- epilogue: bias + store this quarter-tile (left in flight) ----
            int h = h0 + it;
            int g = h >> 2, q = h & 3;
            int row_base;
            if (h < 4 * NDG) {
                int d = g >> 8, b = g & 255;
                row_base = b * SEQ + 1 + d * (NOBJ + 1) + q * 16;
            } else {
                int b = g - NDG;
                row_base = b * SEQ + 1 + NDEMO * (NOBJ + 1) + q * 16;
            }
#pragma unroll
            for (int j = 0; j < 4; ++j) {
                int col = n0 + j * 16 + l15;
#pragma unroll
                for (int r = 0; r < 4; ++r) {
                    int row = row_base + l4 * 4 + r;
                    out[(size_t)row * TOK + col] = acc[j][r] + bv[j];
                }
            }

            bc = bc == 2 ? 0 : bc + 1;
        }

    } else if (blk < ACT_BLKS) {
        // ================= action rows: 8 consecutive groups =================
        int g8 = blk * 8;
        int t = tid;
        float v[8];
        float bb = b_act[t];
#pragma unroll
        for (int r = 0; r < 8; ++r) v[r] = bb;
#pragma unroll
        for (int k = 0; k < 7; ++k) {
            float wv = W_act[k * TOK + t];
#pragma unroll
            for (int r = 0; r < 8; ++r)
                v[r] += demo_act[(size_t)(g8 + r) * 7 + k] * wv;
        }
#pragma unroll
        for (int r = 0; r < 8; ++r) {
            int g = g8 + r;
            int d = g >> 8, b = g & 255;
            out[(size_t)(b * SEQ + (d + 1) * (NOBJ + 1)) * TOK + t] = v[r];
        }

    } else {
        // ================= instr rows: 2 per block, K=768 =================
        int b0 = (blk - ACT_BLKS) * 2;
        int t = tid;
        float* buf = lds;   // 1536 f32 = 6 KB
        const float* src = instr + (size_t)b0 * 768;
#pragma unroll
        for (int i = 0; i < 6; ++i) buf[i * 256 + t] = src[i * 256 + t];
        __syncthreads();
        float a0 = b_instr[t], a1 = a0;
#pragma unroll 4
        for (int k = 0; k < 768; ++k) {
            float wv = W_instr[(size_t)k * TOK + t];
            a0 += buf[k] * wv;
            a1 += buf[768 + k] * wv;
        }
        out[(size_t)b0 * SEQ * TOK + t] = a0;
        out[(size_t)(b0 + 1) * SEQ * TOK + t] = a1;
    }
}

extern "C" void kernel_launch(void* const* d_in, const int* in_sizes, int n_in,
                              void* d_out, int out_size, void* d_ws, size_t ws_size,
                              hipStream_t stream) {
    (void)in_sizes; (void)n_in; (void)out_size; (void)ws_size;
    const float* instr    = (const float*)d_in[0];
    const float* demo_obj = (const float*)d_in[1];
    const float* demo_act = (const float*)d_in[2];
    const float* cur      = (const float*)d_in[3];
    const float* W_instr  = (const float*)d_in[4];
    const float* b_instr  = (const float*)d_in[5];
    const float* W_act    = (const float*)d_in[6];
    const float* b_act    = (const float*)d_in[7];
    const float* W_obj    = (const float*)d_in[8];
    const float* b_obj    = (const float*)d_in[9];
    float* out = (float*)d_out;

    uint16_t* Wf = (uint16_t*)d_ws;   // 128 KB fragment-ordered bf16 weights

    wconv_frag_kernel<<<32, 256, 0, stream>>>(W_obj, Wf);
    fused_kernel<<<TOTAL_BLKS, 256, 0, stream>>>(
        demo_obj, cur, b_obj, (const __bf16*)d_ws,
        demo_act, W_act, b_act, instr, W_instr, b_instr, out);
}

// Round 8
// 157.368 us; speedup vs baseline: 1.5302x; 1.5302x over previous
//
#include <hip/hip_runtime.h>
#include <hip/hip_bf16.h>
#include <stdint.h>

#define TOK   256
#define NOBJ  64
#define NDEMO 16
#define BATCH 256
#define SEQ   1105              /* 1 + 16*65 + 64 */
#define NDG   (NDEMO * BATCH)   /* 4096 demo groups */
#define NGRP  (NDG + BATCH)     /* 4352 total groups */
#define NHT   (NGRP * 2)        /* 8704 half-tiles (32 rows each) */
#define NG    8                 /* half-tiles per obj block */
#define OBJ_BLKS   (NHT / NG)   /* 1088 */
#define ACT_BLKS   512
#define INSTR_BLKS 128
#define TOTAL_BLKS (ACT_BLKS + INSTR_BLKS + OBJ_BLKS)

typedef __bf16 bf16x8 __attribute__((ext_vector_type(8)));
typedef float  f32x4  __attribute__((ext_vector_type(4)));

static __device__ __forceinline__ unsigned pack_bf16x2(float a, float b) {
    unsigned ua = __float_as_uint(a);
    unsigned ub = __float_as_uint(b);
    unsigned ra = (ua + 0x7FFFu + ((ua >> 16) & 1u)) >> 16;
    unsigned rb = (ub + 0x7FFFu + ((ub >> 16) & 1u)) >> 16;
    return (ra & 0xFFFFu) | (rb << 16);
}

static __device__ __forceinline__ uint16_t f32_to_bf16_bits(float a) {
    unsigned ua = __float_as_uint(a);
    return (uint16_t)((ua + 0x7FFFu + ((ua >> 16) & 1u)) >> 16);
}

static __device__ __forceinline__ bf16x8 pack8(float4 lo, float4 hi) {
    union { uint4 u; bf16x8 b; } r;
    r.u.x = pack_bf16x2(lo.x, lo.y);
    r.u.y = pack_bf16x2(lo.z, lo.w);
    r.u.z = pack_bf16x2(hi.x, hi.y);
    r.u.w = pack_bf16x2(hi.z, hi.w);
    return r.b;
}

// direct global->LDS, 16B per lane (dest linear: wave-uniform base + lane*16)
static __device__ __forceinline__ void gload_lds16(const float* g, void* l) {
    __builtin_amdgcn_global_load_lds(
        (const __attribute__((address_space(1))) uint32_t*)g,
        (__attribute__((address_space(3))) uint32_t*)l,
        16, 0, 0);
}

// ---------------------------------------------------------------------------
// Prologue: W_obj (f32 [k=256][t=256]) -> Wf, bf16 in MFMA fragment order:
// chunk q = ((wc*4 + j)*8 + s)*64 + lane  holds W[k = s*32+(lane>>4)*8 .. +7]
// [t = wc*64+j*16+(lane&15)] -- serves as the A-operand (W^T) fragment.
// ---------------------------------------------------------------------------
__global__ void wconv_frag_kernel(const float* __restrict__ W, uint16_t* __restrict__ Wf) {
    int q = blockIdx.x * 256 + threadIdx.x;   // 8192 chunks of 16B
    int lane = q & 63;
    int s  = (q >> 6) & 7;
    int j  = (q >> 9) & 3;
    int wc = (q >> 11) & 3;
    int tcol = wc * 64 + j * 16 + (lane & 15);
    int k0   = s * 32 + (lane >> 4) * 8;
    uint4 w;
    unsigned p[4];
#pragma unroll
    for (int h = 0; h < 4; ++h) {
        float a = W[(size_t)(k0 + 2 * h)     * TOK + tcol];
        float b = W[(size_t)(k0 + 2 * h + 1) * TOK + tcol];
        p[h] = pack_bf16x2(a, b);
    }
    w.x = p[0]; w.y = p[1]; w.z = p[2]; w.w = p[3];
    *reinterpret_cast<uint4*>(Wf + (size_t)q * 8) = w;
}

// ---------------------------------------------------------------------------
// Fused kernel. Grid roles:
//   [0, 512)         : action rows (8 per block)
//   [512, 640)       : instr rows (2 per block)
//   [640, 640+1088)  : obj GEMM, NG=8 32-row half-tiles per block,
//                      double-buffered global_load_lds, counted vmcnt(8),
//                      SWAPPED MFMA operands -> float4 epilogue stores.
// ---------------------------------------------------------------------------
__global__ __launch_bounds__(256, 2) void fused_kernel(
    const float* __restrict__ demo_obj,   // (16,256,64,256)
    const float* __restrict__ cur,        // (256,64,256)
    const float* __restrict__ b_obj,      // (256,)
    const __bf16* __restrict__ Wf,        // fragment-ordered bf16 weights
    const float* __restrict__ demo_act,   // (16,256,7)
    const float* __restrict__ W_act,      // (7,256)
    const float* __restrict__ b_act,      // (256,)
    const float* __restrict__ instr,      // (256,768)
    const float* __restrict__ W_instr,    // (768,256)
    const float* __restrict__ b_instr,    // (256,)
    float* __restrict__ out)              // (256,1105,256)
{
    __shared__ __align__(16) float lds[2 * 32 * TOK];   // 64 KB
    int blk = blockIdx.x;
    int tid = threadIdx.x;

    if (blk >= ACT_BLKS + INSTR_BLKS) {
        // ================= obj GEMM =================
        int ob = blk - (ACT_BLKS + INSTR_BLKS);
        int h0 = ob * NG;
        const float* base = (h0 < 2 * NDG)
            ? demo_obj + (size_t)h0 * (32 * TOK)
            : cur + (size_t)(h0 - 2 * NDG) * (32 * TOK);

        int wave = tid >> 6, lane = tid & 63;
        int l15 = lane & 15, l4 = lane >> 4;
        int n0 = wave * 64;   // this wave's 64 token columns

        auto STAGE = [&](int it, int bsel) {
            const float* sb = base + (size_t)it * (32 * TOK);
            float* dst = lds + bsel * (32 * TOK);
#pragma unroll
            for (int i = 0; i < 8; ++i) {
                int r = i * 4 + wave;
                int gch = r * 64 + (lane ^ (r & 7));   // pre-swizzled global source
                gload_lds16(sb + (size_t)gch * 4, dst + (size_t)(i * 256 + tid) * 4);
            }
        };

        // ---- W preload (A-operand frags): 32 contiguous 1KB wave-loads ----
        bf16x8 wf[4][8];
        {
            const __bf16* fb = Wf + ((size_t)wave * 32 * 64 + lane) * 8;
#pragma unroll
            for (int j = 0; j < 4; ++j)
#pragma unroll
                for (int s = 0; s < 8; ++s)
                    wf[j][s] = *reinterpret_cast<const bf16x8*>(fb + (size_t)(j * 8 + s) * 64 * 8);
        }
        // launder: compiler's wait for W lands here (prologue), not in-loop
#pragma unroll
        for (int j = 0; j < 4; ++j)
#pragma unroll
            for (int s = 0; s < 8; ++s)
                asm volatile("" : "+v"(wf[j][s]));

        // per-lane float4 bias for this lane's 4 consecutive token cols
        f32x4 bv4[4];
#pragma unroll
        for (int j = 0; j < 4; ++j)
            bv4[j] = *reinterpret_cast<const f32x4*>(b_obj + n0 + j * 16 + l4 * 4);

        // ---- stage first two tiles (16 loads/wave in flight) ----
        STAGE(0, 0);
        STAGE(1, 1);

#pragma unroll 1
        for (int it = 0; it < NG; ++it) {
            // FIFO at this point: L_it(8, oldest) then S_{it-1}(8) [or L1 at it=0]
            asm volatile("s_waitcnt vmcnt(8)" ::: "memory");
            __builtin_amdgcn_s_barrier();           // raw: no implicit drain
            __builtin_amdgcn_sched_barrier(0);

            // stage next tile into the buffer read in it-1 (safe: all past barrier)
            if (it + 1 < NG) STAGE(it + 1, (it + 1) & 1);

            const float* buf = lds + (it & 1) * (32 * TOK);

            f32x4 acc[2][4];
#pragma unroll
            for (int i = 0; i < 2; ++i)
#pragma unroll
                for (int j = 0; j < 4; ++j) {
                    f32x4 z = {0.0f, 0.0f, 0.0f, 0.0f};
                    acc[i][j] = z;
                }

#pragma unroll
            for (int s = 0; s < 8; ++s) {
                bf16x8 a[2];   // Act^T B-operand frags: rows i*16+l15, k-chunk by l4
#pragma unroll
                for (int i = 0; i < 2; ++i) {
                    int r = i * 16 + l15;
                    int c0 = s * 8 + l4 * 2;
                    float4 lo = *reinterpret_cast<const float4*>(buf + r * TOK + ((c0 ^ (r & 7)) * 4));
                    float4 hi = *reinterpret_cast<const float4*>(buf + r * TOK + (((c0 + 1) ^ (r & 7)) * 4));
                    a[i] = pack8(lo, hi);
                }
#pragma unroll
                for (int j = 0; j < 4; ++j) {
                    // D = W^T (A) x Act^T (B): D row = token col, D col = seq row
                    acc[0][j] = __builtin_amdgcn_mfma_f32_16x16x32_bf16(wf[j][s], a[0], acc[0][j], 0, 0, 0);
                    acc[1][j] = __builtin_amdgcn_mfma_f32_16x16x32_bf16(wf[j][s], a[1], acc[1][j], 0, 0, 0);
                }
            }

            // ---- epilogue: float4 stores (1 KB per wave instruction) ----
            int h = h0 + it;
            int gg = h >> 1, half = h & 1;
            int row_base;
            if (h < 2 * NDG) {
                int d = gg >> 8, b = gg & 255;
                row_base = b * SEQ + 1 + d * (NOBJ + 1) + half * 32;
            } else {
                int b = gg - NDG;
                row_base = b * SEQ + 1 + NDEMO * (NOBJ + 1) + half * 32;
            }
#pragma unroll
            for (int i = 0; i < 2; ++i) {
                int row = row_base + i * 16 + l15;
#pragma unroll
                for (int j = 0; j < 4; ++j) {
                    f32x4 v = acc[i][j] + bv4[j];
                    *reinterpret_cast<f32x4*>(out + (size_t)row * TOK + n0 + j * 16 + l4 * 4) = v;
                }
            }
        }

    } else if (blk < ACT_BLKS) {
        // ================= action rows: 8 consecutive groups =================
        int g8 = blk * 8;
        int t = tid;
        float v[8];
        float bb = b_act[t];
#pragma unroll
        for (int r = 0; r < 8; ++r) v[r] = bb;
#pragma unroll
        for (int k = 0; k < 7; ++k) {
            float wv = W_act[k * TOK + t];
#pragma unroll
            for (int r = 0; r < 8; ++r)
                v[r] += demo_act[(size_t)(g8 + r) * 7 + k] * wv;
        }
#pragma unroll
        for (int r = 0; r < 8; ++r) {
            int g = g8 + r;
            int d = g >> 8, b = g & 255;
            out[(size_t)(b * SEQ + (d + 1) * (NOBJ + 1)) * TOK + t] = v[r];
        }

    } else {
        // ================= instr rows: 2 per block, K=768 =================
        int b0 = (blk - ACT_BLKS) * 2;
        int t = tid;
        float* buf = lds;   // 1536 f32 = 6 KB
        const float* src = instr + (size_t)b0 * 768;
#pragma unroll
        for (int i = 0; i < 6; ++i) buf[i * 256 + t] = src[i * 256 + t];
        __syncthreads();
        float a0 = b_instr[t], a1 = a0;
#pragma unroll 4
        for (int k = 0; k < 768; ++k) {
            float wv = W_instr[(size_t)k * TOK + t];
            a0 += buf[k] * wv;
            a1 += buf[768 + k] * wv;
        }
        out[(size_t)b0 * SEQ * TOK + t] = a0;
        out[(size_t)(b0 + 1) * SEQ * TOK + t] = a1;
    }
}

extern "C" void kernel_launch(void* const* d_in, const int* in_sizes, int n_in,
                              void* d_out, int out_size, void* d_ws, size_t ws_size,
                              hipStream_t stream) {
    (void)in_sizes; (void)n_in; (void)out_size; (void)ws_size;
    const float* instr    = (const float*)d_in[0];
    const float* demo_obj = (const float*)d_in[1];
    const float* demo_act = (const float*)d_in[2];
    const float* cur      = (const float*)d_in[3];
    const float* W_instr  = (const float*)d_in[4];
    const float* b_instr  = (const float*)d_in[5];
    const float* W_act    = (const float*)d_in[6];
    const float* b_act    = (const float*)d_in[7];
    const float* W_obj    = (const float*)d_in[8];
    const float* b_obj    = (const float*)d_in[9];
    float* out = (float*)d_out;

    uint16_t* Wf = (uint16_t*)d_ws;   // 128 KB fragment-ordered bf16 weights

    wconv_frag_kernel<<<32, 256, 0, stream>>>(W_obj, Wf);
    fused_kernel<<<TOTAL_BLKS, 256, 0, stream>>>(
        demo_obj, cur, b_obj, (const __bf16*)d_ws,
        demo_act, W_act, b_act, instr, W_instr, b_instr, out);
}

// Round 9
// 157.164 us; speedup vs baseline: 1.5322x; 1.0013x over previous
//
#include <hip/hip_runtime.h>
#include <hip/hip_bf16.h>
#include <stdint.h>

#define TOK   256
#define NOBJ  64
#define NDEMO 16
#define BATCH 256
#define SEQ   1105              /* 1 + 16*65 + 64 */
#define NDG   (NDEMO * BATCH)   /* 4096 demo groups */
#define NGRP  (NDG + BATCH)     /* 4352 total groups */
#define NHT   (NGRP * 2)        /* 8704 half-tiles (32 rows each) */
#define NG    8                 /* half-tiles per obj block */
#define OBJ_BLKS   (NHT / NG)   /* 1088 */
#define ACT_BLKS   512
#define INSTR_BLKS 128
#define TOTAL_BLKS (ACT_BLKS + INSTR_BLKS + OBJ_BLKS)

typedef __bf16 bf16x8 __attribute__((ext_vector_type(8)));
typedef float  f32x4  __attribute__((ext_vector_type(4)));

static __device__ __forceinline__ unsigned pack_bf16x2(float a, float b) {
    unsigned ua = __float_as_uint(a);
    unsigned ub = __float_as_uint(b);
    unsigned ra = (ua + 0x7FFFu + ((ua >> 16) & 1u)) >> 16;
    unsigned rb = (ub + 0x7FFFu + ((ub >> 16) & 1u)) >> 16;
    return (ra & 0xFFFFu) | (rb << 16);
}

// direct global->LDS, 16B per lane (dest linear: wave-uniform base + lane*16)
static __device__ __forceinline__ void gload_lds16(const float* g, void* l) {
    __builtin_amdgcn_global_load_lds(
        (const __attribute__((address_space(1))) uint32_t*)g,
        (__attribute__((address_space(3))) uint32_t*)l,
        16, 0, 0);
}

// ---------------------------------------------------------------------------
// Prologue: W_obj (f32 [k=256][t=256]) -> Wf, bf16 in MFMA fragment order:
// chunk q = ((wc*4 + j)*8 + s)*64 + lane  holds W[k = s*32+(lane>>4)*8 .. +7]
// [t = wc*64+j*16+(lane&15)] -- the A-operand (W^T) fragment stream.
// ---------------------------------------------------------------------------
__global__ void wconv_frag_kernel(const float* __restrict__ W, uint16_t* __restrict__ Wf) {
    int q = blockIdx.x * 256 + threadIdx.x;   // 8192 chunks of 16B
    int lane = q & 63;
    int s  = (q >> 6) & 7;
    int j  = (q >> 9) & 3;
    int wc = (q >> 11) & 3;
    int tcol = wc * 64 + j * 16 + (lane & 15);
    int k0   = s * 32 + (lane >> 4) * 8;
    uint4 w;
    unsigned p[4];
#pragma unroll
    for (int h = 0; h < 4; ++h) {
        float a = W[(size_t)(k0 + 2 * h)     * TOK + tcol];
        float b = W[(size_t)(k0 + 2 * h + 1) * TOK + tcol];
        p[h] = pack_bf16x2(a, b);
    }
    w.x = p[0]; w.y = p[1]; w.z = p[2]; w.w = p[3];
    *reinterpret_cast<uint4*>(Wf + (size_t)q * 8) = w;
}

// ---------------------------------------------------------------------------
// Fused kernel. Grid roles:
//   [0, 512)         : action rows (8 per block)
//   [512, 640)       : instr rows (2 per block)
//   [640, 640+1088)  : obj GEMM, NG=8 32-row half-tiles per block.
//   Per tile: DMA f32 -> F (32KB, single) ; convert ONCE (native cvt_pk)
//   into bf16 B tile (16KB, double-buffered, XOR-swizzled) ; pure
//   ds_read_b128->MFMA inner loop ; float4 stores. Counted vmcnt pipeline.
// ---------------------------------------------------------------------------
__global__ __launch_bounds__(256, 2) void fused_kernel(
    const float* __restrict__ demo_obj,   // (16,256,64,256)
    const float* __restrict__ cur,        // (256,64,256)
    const float* __restrict__ b_obj,      // (256,)
    const __bf16* __restrict__ Wf,        // fragment-ordered bf16 weights
    const float* __restrict__ demo_act,   // (16,256,7)
    const float* __restrict__ W_act,      // (7,256)
    const float* __restrict__ b_act,      // (256,)
    const float* __restrict__ instr,      // (256,768)
    const float* __restrict__ W_instr,    // (768,256)
    const float* __restrict__ b_instr,    // (256,)
    float* __restrict__ out)              // (256,1105,256)
{
    __shared__ __align__(16) unsigned char lds_raw[65536];   // 64 KB
    float* F = reinterpret_cast<float*>(lds_raw);            // 32 KB f32 staging
    int blk = blockIdx.x;
    int tid = threadIdx.x;

    if (blk >= ACT_BLKS + INSTR_BLKS) {
        // ================= obj GEMM =================
        int ob = blk - (ACT_BLKS + INSTR_BLKS);
        int h0 = ob * NG;
        const float* base = (h0 < 2 * NDG)
            ? demo_obj + (size_t)h0 * (32 * TOK)
            : cur + (size_t)(h0 - 2 * NDG) * (32 * TOK);

        int wave = tid >> 6, lane = tid & 63;
        int l15 = lane & 15, l4 = lane >> 4;
        int n0 = wave * 64;   // this wave's 64 token columns

        auto STAGE = [&](int it) {
            const float* sb = base + (size_t)it * (32 * TOK);
#pragma unroll
            for (int i = 0; i < 8; ++i)
                gload_lds16(sb + (size_t)(i * 256 + tid) * 4,
                            F + (size_t)(i * 256 + tid) * 4);
        };

        // ---- W preload (A-operand frags): 32 contiguous 1KB wave-loads ----
        bf16x8 wf[4][8];
        {
            const __bf16* fb = Wf + ((size_t)wave * 32 * 64 + lane) * 8;
#pragma unroll
            for (int j = 0; j < 4; ++j)
#pragma unroll
                for (int s = 0; s < 8; ++s)
                    wf[j][s] = *reinterpret_cast<const bf16x8*>(fb + (size_t)(j * 8 + s) * 64 * 8);
        }
#pragma unroll
        for (int j = 0; j < 4; ++j)
#pragma unroll
            for (int s = 0; s < 8; ++s)
                asm volatile("" : "+v"(wf[j][s]));   // force wait in prologue

        // per-lane float4 bias for this lane's 4 consecutive token cols
        f32x4 bv4[4];
#pragma unroll
        for (int j = 0; j < 4; ++j) {
            bv4[j] = *reinterpret_cast<const f32x4*>(b_obj + n0 + j * 16 + l4 * 4);
            asm volatile("" : "+v"(bv4[j]));
        }

        STAGE(0);   // first tile's DMA in flight

#pragma unroll 1
        for (int it = 0; it < NG; ++it) {
            // FIFO: it==0 -> L_0(8). it>=1 -> L_it(8, oldest) + S_{it-1}(8).
            if (it == 0) asm volatile("s_waitcnt vmcnt(0)" ::: "memory");
            else         asm volatile("s_waitcnt vmcnt(8)" ::: "memory");
            __builtin_amdgcn_s_barrier();           // F(it) visible to all waves
            __builtin_amdgcn_sched_barrier(0);

            // ---- convert phase: F (f32) -> B[it&1] (bf16, XOR-swizzled), ONCE ----
            __bf16* B = reinterpret_cast<__bf16*>(lds_raw + 32768 + (it & 1) * 16384);
#pragma unroll
            for (int i = 0; i < 4; ++i) {
                int p = i * 256 + tid;              // 1024 octets of 8 f32
                int row = p >> 5;                   // 32 octets per 256-f32 row
                int c8  = p & 31;
                float4 lo = *reinterpret_cast<const float4*>(F + (size_t)p * 8);
                float4 hi = *reinterpret_cast<const float4*>(F + (size_t)p * 8 + 4);
                bf16x8 o;
                o[0] = (__bf16)lo.x; o[1] = (__bf16)lo.y;
                o[2] = (__bf16)lo.z; o[3] = (__bf16)lo.w;
                o[4] = (__bf16)hi.x; o[5] = (__bf16)hi.y;
                o[6] = (__bf16)hi.z; o[7] = (__bf16)hi.w;
                unsigned off = (unsigned)(row * 512 + c8 * 16) ^ (unsigned)((row & 7) << 4);
                *reinterpret_cast<bf16x8*>(reinterpret_cast<unsigned char*>(B) + off) = o;
            }
            asm volatile("s_waitcnt lgkmcnt(0)" ::: "memory");
            __builtin_amdgcn_sched_barrier(0);
            __builtin_amdgcn_s_barrier();           // B ready; F free
            __builtin_amdgcn_sched_barrier(0);

            // ---- DMA next tile into F (overlaps MFMA phase below) ----
            if (it + 1 < NG) STAGE(it + 1);

            // ---- MFMA phase: pure ds_read_b128 -> mfma ----
            const unsigned char* Bb = lds_raw + 32768 + (it & 1) * 16384;
            f32x4 acc[2][4];
#pragma unroll
            for (int i = 0; i < 2; ++i)
#pragma unroll
                for (int j = 0; j < 4; ++j) {
                    f32x4 z = {0.0f, 0.0f, 0.0f, 0.0f};
                    acc[i][j] = z;
                }

#pragma unroll
            for (int s = 0; s < 8; ++s) {
                bf16x8 a[2];   // Act^T B-operand frags
#pragma unroll
                for (int i = 0; i < 2; ++i) {
                    int r = i * 16 + l15;
                    unsigned off = (unsigned)(r * 512 + s * 64 + l4 * 16) ^ (unsigned)((r & 7) << 4);
                    a[i] = *reinterpret_cast<const bf16x8*>(Bb + off);
                }
#pragma unroll
                for (int j = 0; j < 4; ++j) {
                    // D = W^T (A) x Act^T (B): D row = token col, D col = seq row
                    acc[0][j] = __builtin_amdgcn_mfma_f32_16x16x32_bf16(wf[j][s], a[0], acc[0][j], 0, 0, 0);
                    acc[1][j] = __builtin_amdgcn_mfma_f32_16x16x32_bf16(wf[j][s], a[1], acc[1][j], 0, 0, 0);
                }
            }

            // ---- epilogue: float4 stores (left in flight) ----
            int h = h0 + it;
            int gg = h >> 1, half = h & 1;
            int row_base;
            if (h < 2 * NDG) {
                int d = gg >> 8, b = gg & 255;
                row_base = b * SEQ + 1 + d * (NOBJ + 1) + half * 32;
            } else {
                int b = gg - NDG;
                row_base = b * SEQ + 1 + NDEMO * (NOBJ + 1) + half * 32;
            }
#pragma unroll
            for (int i = 0; i < 2; ++i) {
                int row = row_base + i * 16 + l15;
#pragma unroll
                for (int j = 0; j < 4; ++j) {
                    f32x4 v = acc[i][j] + bv4[j];
                    *reinterpret_cast<f32x4*>(out + (size_t)row * TOK + n0 + j * 16 + l4 * 4) = v;
                }
            }
        }

    } else if (blk < ACT_BLKS) {
        // ================= action rows: 8 consecutive groups =================
        int g8 = blk * 8;
        int t = tid;
        float v[8];
        float bb = b_act[t];
#pragma unroll
        for (int r = 0; r < 8; ++r) v[r] = bb;
#pragma unroll
        for (int k = 0; k < 7; ++k) {
            float wv = W_act[k * TOK + t];
#pragma unroll
            for (int r = 0; r < 8; ++r)
                v[r] += demo_act[(size_t)(g8 + r) * 7 + k] * wv;
        }
#pragma unroll
        for (int r = 0; r < 8; ++r) {
            int g = g8 + r;
            int d = g >> 8, b = g & 255;
            out[(size_t)(b * SEQ + (d + 1) * (NOBJ + 1)) * TOK + t] = v[r];
        }

    } else {
        // ================= instr rows: 2 per block, K=768 =================
        int b0 = (blk - ACT_BLKS) * 2;
        int t = tid;
        float* buf = F;   // 1536 f32 = 6 KB
        const float* src = instr + (size_t)b0 * 768;
#pragma unroll
        for (int i = 0; i < 6; ++i) buf[i * 256 + t] = src[i * 256 + t];
        __syncthreads();
        float a0 = b_instr[t], a1 = a0;
#pragma unroll 4
        for (int k = 0; k < 768; ++k) {
            float wv = W_instr[(size_t)k * TOK + t];
            a0 += buf[k] * wv;
            a1 += buf[768 + k] * wv;
        }
        out[(size_t)b0 * SEQ * TOK + t] = a0;
        out[(size_t)(b0 + 1) * SEQ * TOK + t] = a1;
    }
}

extern "C" void kernel_launch(void* const* d_in, const int* in_sizes, int n_in,
                              void* d_out, int out_size, void* d_ws, size_t ws_size,
                              hipStream_t stream) {
    (void)in_sizes; (void)n_in; (void)out_size; (void)ws_size;
    const float* instr    = (const float*)d_in[0];
    const float* demo_obj = (const float*)d_in[1];
    const float* demo_act = (const float*)d_in[2];
    const float* cur      = (const float*)d_in[3];
    const float* W_instr  = (const float*)d_in[4];
    const float* b_instr  = (const float*)d_in[5];
    const float* W_act    = (const float*)d_in[6];
    const float* b_act    = (const float*)d_in[7];
    const float* W_obj    = (const float*)d_in[8];
    const float* b_obj    = (const float*)d_in[9];
    float* out = (float*)d_out;

    uint16_t* Wf = (uint16_t*)d_ws;   // 128 KB fragment-ordered bf16 weights

    wconv_frag_kernel<<<32, 256, 0, stream>>>(W_obj, Wf);
    fused_kernel<<<TOTAL_BLKS, 256, 0, stream>>>(
        demo_obj, cur, b_obj, (const __bf16*)d_ws,
        demo_act, W_act, b_act, instr, W_instr, b_instr, out);
}